// Round 1
// baseline (455.730 us; speedup 1.0000x reference)
//
#include <hip/hip_runtime.h>
#include <hip/hip_bf16.h>

typedef __bf16 bf16x8 __attribute__((ext_vector_type(8)));
typedef float  f32x4  __attribute__((ext_vector_type(4)));

#define H    128
#define XS   128
#define KCH  8
#define NT   8
#define BM   32
#define PAD_K  136   // 128+8 bf16 -> 272B stride (== 4 banks mod 32, 2-way max)
#define PAD_K2 264   // 256+8
#define PAD_KB 72    // 64+8

__device__ __forceinline__ float fsigm(float v){ return 1.f/(1.f+__expf(-v)); }
__device__ __forceinline__ float ftanh(float v){
  v = fminf(fmaxf(v,-15.f),15.f);
  float e = __expf(2.f*v);
  return (e-1.f)/(e+1.f);
}

// ws int layout: [0..8) cnt, [8..16) cursor, [16..25) offs, [25] type stride, [32..32+N) idx
__global__ void k_init(int* ws){
  int t = threadIdx.x;
  if (t < 25) ws[t] = 0;
}

__global__ void k_detect(const int* __restrict__ type_id, int* ws){
  // if type_id is really int64, every odd int32 word (high half) is 0
  __shared__ int nz;
  if (threadIdx.x == 0) nz = 0;
  __syncthreads();
  int v = type_id[threadIdx.x];
  if ((threadIdx.x & 1) && v != 0) atomicAdd(&nz, 1);
  __syncthreads();
  if (threadIdx.x == 0) ws[25] = (nz == 0) ? 2 : 1;
}

__global__ void k_count(const int* __restrict__ type_id, int* __restrict__ ws, int N){
  __shared__ int h[NT];
  int tid = threadIdx.x;
  if (tid < NT) h[tid] = 0;
  __syncthreads();
  int stride = ws[25];
  int i = blockIdx.x*blockDim.x + tid;
  if (i < N) atomicAdd(&h[type_id[(size_t)i*stride]], 1);
  __syncthreads();
  if (tid < NT) atomicAdd(&ws[tid], h[tid]);
}

__global__ void k_scan(int* ws){
  int* cnt = ws; int* cur = ws+8; int* offs = ws+16;
  int s = 0;
  for (int t=0;t<NT;++t){ offs[t]=s; cur[t]=s; s+=cnt[t]; }
  offs[NT]=s;
}

__global__ void k_scatter(const int* __restrict__ type_id, int* __restrict__ ws, int N){
  __shared__ int h[NT], base[NT];
  int tid = threadIdx.x;
  if (tid < NT) h[tid] = 0;
  __syncthreads();
  int stride = ws[25];
  int i = blockIdx.x*blockDim.x + tid;
  int t = 0, lp = 0;
  if (i < N){ t = type_id[(size_t)i*stride]; lp = atomicAdd(&h[t], 1); }
  __syncthreads();
  if (tid < NT) base[tid] = atomicAdd(&ws[8+tid], h[tid]);
  __syncthreads();
  if (i < N) ws[32 + base[t] + lp] = i;
}

__global__ __launch_bounds__(256,2) void k_main(
  const float* __restrict__ x, const float* __restrict__ n_h, const float* __restrict__ n_c,
  const float* __restrict__ W_iou, const float* __restrict__ U_iou, const float* __restrict__ b_iou,
  const float* __restrict__ U_f, const float* __restrict__ b_f,
  const int* __restrict__ ws, float* __restrict__ out, int N, int tiles)
{
  int t    = blockIdx.x / tiles;
  int tile = blockIdx.x % tiles;
  const int* offs = ws + 16;
  int bstart = offs[t];
  int cnt = offs[t+1] - bstart;
  if (tile*BM >= cnt) return;
  const int* idxb = ws + 32;

  __shared__ union {
    __bf16 uf[H][PAD_K];    // U_f[t] transposed: uf[outcol][k]
    __bf16 bt[H][PAD_KB];   // iou weight chunk:  bt[outcol][k_local]
  } wt;
  __shared__ __bf16 nh[BM][PAD_K];     // n_h tile for one child slot
  __shared__ __bf16 act[BM][PAD_K2];   // [x | h_sum] bf16
  __shared__ int nodes[BM];

  int tid  = threadIdx.x;
  int lane = tid & 63, wave = tid >> 6;
  int rw = wave & 1, cw = wave >> 1;   // wave -> rows rw*16, cols cw*64
  int l15 = lane & 15, l4 = lane >> 4;

  if (tid < BM){
    int p = tile*BM + tid;
    nodes[tid] = idxb[bstart + (p < cnt ? p : 0)];
  }

  // stage U_f[t] transposed into LDS (f32 -> bf16)
  {
    const float* Uft = U_f + (size_t)t*H*H;
    int k0 = tid >> 5;
    int c0 = (tid & 31) * 4;
    #pragma unroll
    for (int it=0; it<16; ++it){
      int k = k0 + it*8;
      float4 v = *(const float4*)(Uft + (size_t)k*H + c0);
      wt.uf[c0+0][k] = (__bf16)v.x;
      wt.uf[c0+1][k] = (__bf16)v.y;
      wt.uf[c0+2][k] = (__bf16)v.z;
      wt.uf[c0+3][k] = (__bf16)v.w;
    }
  }
  __syncthreads();

  // per-lane constants (C/D frag: col = lane&15, row = 4*(lane>>4)+reg)
  int nds[4]; bool val[4]; int colf[4]; float bfv[4];
  #pragma unroll
  for (int r=0;r<4;++r){
    int rr = rw*16 + l4*4 + r;
    nds[r] = nodes[rr];
    val[r] = (tile*BM + rr) < cnt;
  }
  #pragma unroll
  for (int f=0;f<4;++f){
    colf[f] = cw*64 + f*16 + l15;
    bfv[f]  = b_f[t*H + colf[f]];
  }

  int mrow = tid >> 3;             // staging: 8 threads per node row
  int mcol = (tid & 7) * 16;
  const float* nh_base = n_h + (size_t)nodes[mrow]*(KCH*H) + mcol;
  const float* x_base  = x   + (size_t)nodes[mrow]*XS + mcol;

  float hsum[16];
  #pragma unroll
  for (int j=0;j<16;++j) hsum[j] = 0.f;
  f32x4 cacc[4];
  #pragma unroll
  for (int f=0;f<4;++f) cacc[f] = (f32x4){0.f,0.f,0.f,0.f};

  // ---- phase B: per-child GEMM [32x128] = n_h[:,k,:] @ U_f[t], f-gate, c_aggr ----
  for (int k=0; k<KCH; ++k){
    const float4* p = (const float4*)(nh_base + k*H);
    float4 a0=p[0], a1=p[1], a2=p[2], a3=p[3];
    hsum[0]+=a0.x;  hsum[1]+=a0.y;  hsum[2]+=a0.z;  hsum[3]+=a0.w;
    hsum[4]+=a1.x;  hsum[5]+=a1.y;  hsum[6]+=a1.z;  hsum[7]+=a1.w;
    hsum[8]+=a2.x;  hsum[9]+=a2.y;  hsum[10]+=a2.z; hsum[11]+=a2.w;
    hsum[12]+=a3.x; hsum[13]+=a3.y; hsum[14]+=a3.z; hsum[15]+=a3.w;
    bf16x8 w0, w1;
    w0[0]=(__bf16)a0.x; w0[1]=(__bf16)a0.y; w0[2]=(__bf16)a0.z; w0[3]=(__bf16)a0.w;
    w0[4]=(__bf16)a1.x; w0[5]=(__bf16)a1.y; w0[6]=(__bf16)a1.z; w0[7]=(__bf16)a1.w;
    w1[0]=(__bf16)a2.x; w1[1]=(__bf16)a2.y; w1[2]=(__bf16)a2.z; w1[3]=(__bf16)a2.w;
    w1[4]=(__bf16)a3.x; w1[5]=(__bf16)a3.y; w1[6]=(__bf16)a3.z; w1[7]=(__bf16)a3.w;
    *(bf16x8*)&nh[mrow][mcol]   = w0;
    *(bf16x8*)&nh[mrow][mcol+8] = w1;
    __syncthreads();

    f32x4 fa[4];
    #pragma unroll
    for (int f=0;f<4;++f) fa[f] = (f32x4){0.f,0.f,0.f,0.f};
    #pragma unroll
    for (int kk=0; kk<4; ++kk){
      bf16x8 av = *(const bf16x8*)&nh[rw*16 + l15][kk*32 + l4*8];
      #pragma unroll
      for (int f=0;f<4;++f){
        bf16x8 bv = *(const bf16x8*)&wt.uf[colf[f]][kk*32 + l4*8];
        fa[f] = __builtin_amdgcn_mfma_f32_16x16x32_bf16(av, bv, fa[f], 0,0,0);
      }
    }
    #pragma unroll
    for (int f=0;f<4;++f){
      #pragma unroll
      for (int r=0;r<4;++r){
        float fg = fsigm(fa[f][r] + bfv[f]);
        cacc[f][r] += fg * n_c[(size_t)nds[r]*(KCH*H) + k*H + colf[f]];
      }
    }
    __syncthreads();   // nh reads done before next stage overwrites
  }

  // stage act = [x | h_sum] as bf16
  {
    const float4* px = (const float4*)x_base;
    float4 x0=px[0], x1=px[1], x2=px[2], x3=px[3];
    bf16x8 w0,w1,w2,w3;
    w0[0]=(__bf16)x0.x; w0[1]=(__bf16)x0.y; w0[2]=(__bf16)x0.z; w0[3]=(__bf16)x0.w;
    w0[4]=(__bf16)x1.x; w0[5]=(__bf16)x1.y; w0[6]=(__bf16)x1.z; w0[7]=(__bf16)x1.w;
    w1[0]=(__bf16)x2.x; w1[1]=(__bf16)x2.y; w1[2]=(__bf16)x2.z; w1[3]=(__bf16)x2.w;
    w1[4]=(__bf16)x3.x; w1[5]=(__bf16)x3.y; w1[6]=(__bf16)x3.z; w1[7]=(__bf16)x3.w;
    #pragma unroll
    for (int j=0;j<8;++j){ w2[j]=(__bf16)hsum[j]; w3[j]=(__bf16)hsum[8+j]; }
    *(bf16x8*)&act[mrow][mcol]        = w0;
    *(bf16x8*)&act[mrow][mcol+8]      = w1;
    *(bf16x8*)&act[mrow][H+mcol]      = w2;
    *(bf16x8*)&act[mrow][H+mcol+8]    = w3;
  }
  __syncthreads();

  // ---- phase A: iou[32x384] = [x|hsum] @ [W_iou;U_iou], per-gate chunks of 128 cols ----
  f32x4 iou[3][4];
  #pragma unroll
  for (int g=0; g<3; ++g)
    #pragma unroll
    for (int f=0;f<4;++f) iou[g][f] = (f32x4){0.f,0.f,0.f,0.f};

  #pragma unroll
  for (int g=0; g<3; ++g){
    for (int kc=0; kc<4; ++kc){
      { // stage bt[c][kk] = Wcat[kc*64+kk][g*128+c]
        int kk = tid >> 2;
        int cb = (tid & 3) * 32;
        int K0 = kc*64 + kk;
        const float* src = (K0 < H)
          ? (W_iou + ((size_t)t*H + K0)*(3*H) + g*H)
          : (U_iou + ((size_t)t*H + (K0-H))*(3*H) + g*H);
        #pragma unroll
        for (int i2=0;i2<8;++i2){
          int c = cb + i2*4;
          float4 v = *(const float4*)(src + c);
          wt.bt[c+0][kk]=(__bf16)v.x;
          wt.bt[c+1][kk]=(__bf16)v.y;
          wt.bt[c+2][kk]=(__bf16)v.z;
          wt.bt[c+3][kk]=(__bf16)v.w;
        }
      }
      __syncthreads();
      #pragma unroll
      for (int kk2=0; kk2<2; ++kk2){
        bf16x8 av = *(const bf16x8*)&act[rw*16 + l15][kc*64 + kk2*32 + l4*8];
        #pragma unroll
        for (int f=0;f<4;++f){
          bf16x8 bv = *(const bf16x8*)&wt.bt[cw*64 + f*16 + l15][kk2*32 + l4*8];
          iou[g][f] = __builtin_amdgcn_mfma_f32_16x16x32_bf16(av, bv, iou[g][f], 0,0,0);
        }
      }
      __syncthreads();
    }
  }

  // ---- epilogue: gates + store ----
  #pragma unroll
  for (int f=0;f<4;++f){
    float bi = b_iou[t*(3*H) +        colf[f]];
    float bo = b_iou[t*(3*H) + H   +  colf[f]];
    float bu = b_iou[t*(3*H) + 2*H +  colf[f]];
    #pragma unroll
    for (int r=0;r<4;++r){
      if (!val[r]) continue;
      float ig = iou[0][f][r] + bi;
      float og = iou[1][f][r] + bo;
      float ug = iou[2][f][r] + bu;
      float cv = fsigm(ig)*ftanh(ug) + cacc[f][r];
      float hv = fsigm(og)*ftanh(cv);
      size_t oh = (size_t)nds[r]*H + colf[f];
      out[oh] = hv;
      out[(size_t)N*H + oh] = cv;
    }
  }
}

extern "C" void kernel_launch(void* const* d_in, const int* in_sizes, int n_in,
                              void* d_out, int out_size, void* d_ws, size_t ws_size,
                              hipStream_t stream){
  const float* x      = (const float*)d_in[0];
  const float* n_h    = (const float*)d_in[1];
  const float* n_c    = (const float*)d_in[2];
  const int*   typ    = (const int*)d_in[3];
  const float* W_iou  = (const float*)d_in[4];
  const float* U_iou  = (const float*)d_in[5];
  const float* b_iou  = (const float*)d_in[6];
  const float* U_f    = (const float*)d_in[7];
  const float* b_f    = (const float*)d_in[8];
  float* out = (float*)d_out;
  int*   ws  = (int*)d_ws;
  int N = in_sizes[0] / XS;
  int nb = (N + 255) / 256;
  int tiles = (N + BM - 1) / BM;

  hipLaunchKernelGGL(k_init,    dim3(1),       dim3(32),  0, stream, ws);
  hipLaunchKernelGGL(k_detect,  dim3(1),       dim3(256), 0, stream, typ, ws);
  hipLaunchKernelGGL(k_count,   dim3(nb),      dim3(256), 0, stream, typ, ws, N);
  hipLaunchKernelGGL(k_scan,    dim3(1),       dim3(1),   0, stream, ws);
  hipLaunchKernelGGL(k_scatter, dim3(nb),      dim3(256), 0, stream, typ, ws, N);
  hipLaunchKernelGGL(k_main,    dim3(NT*tiles), dim3(256), 0, stream,
                     x, n_h, n_c, W_iou, U_iou, b_iou, U_f, b_f, ws, out, N, tiles);
}